// Round 11
// baseline (110.076 us; speedup 1.0000x reference)
//
#include <hip/hip_runtime.h>

// Problem constants (fixed by reference: B=32,D=64,H=32,W=32,K=2048)
#define N_PIX 32768   // B*H*W
#define DIM   64
#define KCODE 2048

typedef __attribute__((ext_vector_type(8))) short bf16x8;   // 8 bf16 = 4 VGPR
typedef __attribute__((ext_vector_type(4))) float f32x4;    // MFMA C/D

// bf16 round-to-nearest-even (manual, deterministic)
__device__ inline unsigned short f2bf(float v) {
    unsigned int u = __float_as_uint(v);
    return (unsigned short)((u + 0x7FFFu + ((u >> 16) & 1u)) >> 16);
}
__device__ inline float bf2f(unsigned short b) {
    return __uint_as_float(((unsigned int)b) << 16);
}

// ---------------------------------------------------------------------------
// convert_b: split codebook into 3 bf16 planes (fragment-major 256B units
// [n 0..15][j 0..7]) + e_sq. 8 blocks x 256 thr. e = h+m+l, err ~2^-27|e|.
// ---------------------------------------------------------------------------
__global__ __launch_bounds__(256)
void convert_b_kernel(const float* __restrict__ cb, unsigned short* __restrict__ Bg,
                      float* __restrict__ esq) {
    const int n = blockIdx.x * 256 + threadIdx.x;   // code id 0..2047
    const float* src = cb + (size_t)n * DIM;
    const int ntile = n >> 4, ni = n & 15;
    char* outb = (char*)Bg;
    float s = 0.f;
#pragma unroll
    for (int kb = 0; kb < 8; ++kb) {
        alignas(16) unsigned short hv[8], mv[8], lv[8];
#pragma unroll
        for (int j = 0; j < 8; ++j) {
            float v = src[kb * 8 + j];
            s = fmaf(v, v, s);
            unsigned short h = f2bf(v);
            float r1 = v - bf2f(h);
            unsigned short m = f2bf(r1);
            unsigned short l = f2bf(r1 - bf2f(m));
            hv[j] = h; mv[j] = m; lv[j] = l;
        }
        size_t u = ((((size_t)ntile) * 8 + kb) << 8) + ni * 16;
        *(uint4*)(outb + u)          = *(uint4*)hv;      // plane stride 256 KB
        *(uint4*)(outb + 262144 + u) = *(uint4*)mv;
        *(uint4*)(outb + 524288 + u) = *(uint4*)lv;
    }
    esq[n] = s;
}

// MFMA pass with LITERAL plane indices (SROA lesson: no array[array[i]]).
#define DO_PASS(APL, BPL)                                                    \
    _Pragma("unroll") for (int ks = 0; ks < 2; ++ks)                         \
    _Pragma("unroll") for (int mt = 0; mt < 2; ++mt)                         \
        acc[mt] = __builtin_amdgcn_mfma_f32_16x16x32_bf16(                   \
            af[APL][mt][ks], bfr[BPL][ks], acc[mt], 0, 0, 0);

// Stage one 1 KB fragment-major unit of Bg into the LDS ring via DMA:
// unit u -> (plane, wn-group, ks); dest = wave-uniform base + lane*16 (HW).
__device__ __forceinline__ void stage_unit(const char* BgB, char* ringBase,
                                           int u, int it, int slotOff, int lane) {
    const int pl = u >> 3, rem = u & 7, g = rem >> 1, ks = rem & 1;
    const char* gsrc = BgB + (size_t)pl * 262144 + (size_t)(g * 32 + it) * 2048
                     + ks * 1024 + lane * 16;
    char* ldst = ringBase + slotOff + pl * 8192 + g * 2048 + ks * 1024;
    __builtin_amdgcn_global_load_lds(
        (const __attribute__((address_space(1))) void*)gsrc,
        (__attribute__((address_space(3))) void*)ldst, 16, 0, 0);
}

// ---------------------------------------------------------------------------
// Fused dist+argmin+gather. Grid 256 (1 block/CU), block 1024 = 16 waves
// (4 wm-groups x 4 wn-groups). Block owns 128 px x all 2048 codes.
//   r10 lesson: B frags from global gave 96 KB/CU-iter of L2 traffic (4x
//   duplicated across wm-pairs/blocks) ~2x the MFMA time -> L2-BW-bound at
//   MfmaUtil 42%. Now B is staged ONCE per CU into a 2-slot LDS ring via
//   global_load_lds DMA (24 KB/iter; layout is exactly wave-uniform-base +
//   lane*16), waves ds_read their frags: VMEM drops 4x, LDS reads 857 cyc
//   < MFMA 932 cyc -> MFMA becomes the tallest pipe.
//   One __syncthreads per iter; its vmcnt drain hits DMA issued a full
//   iter earlier (cheap). 6 bf16 passes (hl,lh,mm,hm,mh,hh small->large),
//   exact to ~2^-23 rel; argmin per-lane (n ascending -> strict <),
//   shfl-16 col-reduce, LDS wn-reduce, lex (d,idx) = numpy first-min.
// ---------------------------------------------------------------------------
__global__ __launch_bounds__(1024, 4)
void dist_fused_kernel(const float* __restrict__ laten,
                       const unsigned short* __restrict__ Bg,
                       const float* __restrict__ esq,
                       const float* __restrict__ cb,
                       float* __restrict__ out0, float* __restrict__ out1) {
    __shared__ __align__(16) char ring[49152];   // 2 x 24 KB B ring; A staging
    __shared__ float esqS[2048];                 // 8 KB

    const int tid  = threadIdx.x;
    const int lane = tid & 63;
    const int wave = tid >> 6;                   // 0..15
    const int wm   = wave & 3;                   // 32-px group
    const int wn   = wave >> 2;                  // 512-code group
    const int quad = lane >> 4, col = lane & 15;
    const int bx = blockIdx.x;
    const int bb = bx >> 3, hw0 = (bx & 7) * 128;   // 128 px contiguous in hw

    const char* BgB = (const char*)Bg;

    // ---- stage A into ring (48 KB transient): split 8 dims of pixel p ----
    {
        const int p = tid & 127, dg = tid >> 7;  // dg 0..7 = kb unit
        const float* srcA = laten + (size_t)bb * 65536 + (size_t)dg * 8192 + hw0 + p;
        const int mt = p >> 4, mi = p & 15;      // mtile 0..7
        alignas(16) unsigned short hv[8], mv[8], lv[8];
#pragma unroll
        for (int j = 0; j < 8; ++j) {
            float v = srcA[(size_t)j << 10];     // coalesced across p
            unsigned short h = f2bf(v);
            float r1 = v - bf2f(h);
            unsigned short m = f2bf(r1);
            unsigned short l = f2bf(r1 - bf2f(m));
            hv[j] = h; mv[j] = m; lv[j] = l;
        }
        int u = ((mt * 8 + dg) << 8) + mi * 16;
        *(uint4*)(ring + u)         = *(uint4*)hv;   // plane h (16 KB stride)
        *(uint4*)(ring + 16384 + u) = *(uint4*)mv;   // plane m
        *(uint4*)(ring + 32768 + u) = *(uint4*)lv;   // plane l
    }
    // stage e_sq (2 floats/thread)
    *(float2*)(esqS + tid * 2) = *(const float2*)(esq + tid * 2);
    __syncthreads();

    // ---- A fragments -> VGPRs: wave's 32-px group (48 regs resident) ----
    bf16x8 af[3][2][2];
#pragma unroll
    for (int pl = 0; pl < 3; ++pl)
#pragma unroll
        for (int mt = 0; mt < 2; ++mt)
#pragma unroll
            for (int ks = 0; ks < 2; ++ks)
                af[pl][mt][ks] = *(const bf16x8*)(ring + pl * 16384
                    + (((wm * 2 + mt) * 8 + ks * 4 + quad) << 8) + col * 16);
    __syncthreads();   // af reads drained before DMA clobbers the ring

    // ---- stage B tile 0 into slot 0 (24 units: waves 0..15 + 0..7) ----
    stage_unit(BgB, ring, wave, 0, 0, lane);
    if (wave < 8) stage_unit(BgB, ring, 16 + wave, 0, 0, lane);
    __syncthreads();   // drains each wave's own DMA (vmcnt 0) -> slot 0 ready

    float best[2][4];
    int   bidx[2][4];
#pragma unroll
    for (int mt = 0; mt < 2; ++mt)
#pragma unroll
        for (int r = 0; r < 4; ++r) { best[mt][r] = 3.4e38f; bidx[mt][r] = 0; }

    for (int it = 0; it < 32; ++it) {
        // issue next tile's DMA first: in flight through this iter's MFMAs
        if (it < 31) {
            const int slotOff = ((it + 1) & 1) * 24576;
            stage_unit(BgB, ring, wave, it + 1, slotOff, lane);
            if (wave < 8) stage_unit(BgB, ring, 16 + wave, it + 1, slotOff, lane);
        }

        // B fragments for this iter from LDS (6 contiguous ds_read_b128)
        const char* rb = ring + (it & 1) * 24576 + wn * 2048;
        bf16x8 bfr[3][2];
#pragma unroll
        for (int pl = 0; pl < 3; ++pl)
#pragma unroll
            for (int ks = 0; ks < 2; ++ks)
                bfr[pl][ks] = *(const bf16x8*)(rb + pl * 8192 + ks * 1024 + lane * 16);

        f32x4 acc[2];
#pragma unroll
        for (int mt = 0; mt < 2; ++mt) acc[mt] = {0.f, 0.f, 0.f, 0.f};

        // 6 passes small->large (hl, lh, mm, hm, mh, hh) — literal planes
        DO_PASS(0, 2)
        DO_PASS(2, 0)
        DO_PASS(1, 1)
        DO_PASS(0, 1)
        DO_PASS(1, 0)
        DO_PASS(0, 0)

        // running argmin; per-lane n strictly ascends across it
        const int n = wn * 512 + it * 16 + col;
        const float e = esqS[n];
#pragma unroll
        for (int mt = 0; mt < 2; ++mt)
#pragma unroll
            for (int r = 0; r < 4; ++r) {
                float d = fmaf(-2.f, acc[mt][r], e);
                if (d < best[mt][r]) { best[mt][r] = d; bidx[mt][r] = n; }
            }

        // one barrier/iter: drains own DMA (issued ~a full iter ago, landed)
        // and publishes slot (it+1) for everyone; guards slot reuse.
        __syncthreads();
    }

    // ---- reduce: shfl over 16 cols, then LDS over the 4 wn groups ----
    float* redD = (float*)ring;              // [128][4]
    int*   redI = (int*)(ring + 2048);       // [128][4]
    int*   idxF = (int*)(ring + 4096);       // [128]
#pragma unroll
    for (int mt = 0; mt < 2; ++mt)
#pragma unroll
        for (int r = 0; r < 4; ++r) {
            float d = best[mt][r];
            int   i = bidx[mt][r];
#pragma unroll
            for (int m = 1; m < 16; m <<= 1) {
                float od = __shfl_xor(d, m, 16);
                int   oi = __shfl_xor(i, m, 16);
                if (od < d || (od == d && oi < i)) { d = od; i = oi; }
            }
            if (col == 0) {
                int row = (wm * 2 + mt) * 16 + quad * 4 + r;   // pixel 0..127
                redD[row * 4 + wn] = d;
                redI[row * 4 + wn] = i;
            }
        }
    __syncthreads();

    if (tid < 128) {
        float bd = redD[tid * 4]; int bi = redI[tid * 4];
#pragma unroll
        for (int w = 1; w < 4; ++w) {
            float d = redD[tid * 4 + w]; int i = redI[tid * 4 + w];
            if (d < bd || (d == bd && i < bi)) { bd = d; bi = i; }
        }
        out0[bx * 128 + tid] = (float)bi;
        idxF[tid] = bi;
    }
    __syncthreads();

    // ---- fused gather: 128 px x 64 dims from the ORIGINAL fp32 codebook ----
    const int p = tid & 127, dg = tid >> 7;          // dg: 8 dims each
    const int idx = idxF[p];
    const float4* srcr = (const float4*)(cb + ((size_t)idx << 6) + dg * 8);
    float* o = out1 + (size_t)bb * 65536 + (size_t)dg * 8192 + hw0 + p;
    float4 v0 = srcr[0], v1 = srcr[1];
    o[(size_t)0 << 10] = v0.x; o[(size_t)1 << 10] = v0.y;
    o[(size_t)2 << 10] = v0.z; o[(size_t)3 << 10] = v0.w;
    o[(size_t)4 << 10] = v1.x; o[(size_t)5 << 10] = v1.y;
    o[(size_t)6 << 10] = v1.z; o[(size_t)7 << 10] = v1.w;
}

// ---------------------------------------------------------------------------
extern "C" void kernel_launch(void* const* d_in, const int* in_sizes, int n_in,
                              void* d_out, int out_size, void* d_ws, size_t ws_size,
                              hipStream_t stream) {
    const float* laten = (const float*)d_in[0];   // (32,64,32,32) fp32
    const float* cb    = (const float*)d_in[1];   // (2048,64) fp32

    float* out0 = (float*)d_out;                  // indices as float, N_PIX
    float* out1 = (float*)d_out + N_PIX;          // quant_laten, 2M

    // ws layout: esq 8 KB | Bg 768 KB   (~776 KB total)
    float* esq = (float*)d_ws;
    unsigned short* Bg = (unsigned short*)(esq + 2048);

    convert_b_kernel<<<8, 256, 0, stream>>>(cb, Bg, esq);

    dist_fused_kernel<<<256, 1024, 0, stream>>>(laten, Bg, esq, cb, out0, out1);
}

// Round 12
// 107.422 us; speedup vs baseline: 1.0247x; 1.0247x over previous
//
#include <hip/hip_runtime.h>

// Problem constants (fixed by reference: B=32,D=64,H=32,W=32,K=2048)
#define N_PIX 32768   // B*H*W
#define DIM   64
#define KCODE 2048

typedef __attribute__((ext_vector_type(8))) short bf16x8;   // 8 bf16 = 4 VGPR
typedef __attribute__((ext_vector_type(4))) float f32x4;    // MFMA C/D

// bf16 round-to-nearest-even (manual, deterministic)
__device__ inline unsigned short f2bf(float v) {
    unsigned int u = __float_as_uint(v);
    return (unsigned short)((u + 0x7FFFu + ((u >> 16) & 1u)) >> 16);
}
__device__ inline float bf2f(unsigned short b) {
    return __uint_as_float(((unsigned int)b) << 16);
}

// ---------------------------------------------------------------------------
// convert_b: split codebook into 3 bf16 planes (fragment-major 256B units
// [n 0..15][j 0..7]) + e_sq. 8 blocks x 256 thr. e = h+m+l, err ~2^-27|e|.
// ---------------------------------------------------------------------------
__global__ __launch_bounds__(256)
void convert_b_kernel(const float* __restrict__ cb, unsigned short* __restrict__ Bg,
                      float* __restrict__ esq) {
    const int n = blockIdx.x * 256 + threadIdx.x;   // code id 0..2047
    const float* src = cb + (size_t)n * DIM;
    const int ntile = n >> 4, ni = n & 15;
    char* outb = (char*)Bg;
    float s = 0.f;
#pragma unroll
    for (int kb = 0; kb < 8; ++kb) {
        alignas(16) unsigned short hv[8], mv[8], lv[8];
#pragma unroll
        for (int j = 0; j < 8; ++j) {
            float v = src[kb * 8 + j];
            s = fmaf(v, v, s);
            unsigned short h = f2bf(v);
            float r1 = v - bf2f(h);
            unsigned short m = f2bf(r1);
            unsigned short l = f2bf(r1 - bf2f(m));
            hv[j] = h; mv[j] = m; lv[j] = l;
        }
        size_t u = ((((size_t)ntile) * 8 + kb) << 8) + ni * 16;
        *(uint4*)(outb + u)          = *(uint4*)hv;      // plane stride 256 KB
        *(uint4*)(outb + 262144 + u) = *(uint4*)mv;
        *(uint4*)(outb + 524288 + u) = *(uint4*)lv;
    }
    esq[n] = s;
}

// MFMA pass with LITERAL plane indices (SROA lesson: no array[array[i]]).
#define DO_PASS(APL, BPL)                                                    \
    _Pragma("unroll") for (int ks = 0; ks < 2; ++ks)                         \
    _Pragma("unroll") for (int mt = 0; mt < 2; ++mt)                         \
        acc[mt] = __builtin_amdgcn_mfma_f32_16x16x32_bf16(                   \
            af[APL][mt][ks], bfr[BPL][ks], acc[mt], 0, 0, 0);

// ds_read one plane's 2 B-fragments from the ring slot (consumption order
// at call sites: plane 2 first so DO_PASS(0,2) starts at partial lgkmcnt).
#define LOAD_BFR(PL)                                                         \
    _Pragma("unroll") for (int ks = 0; ks < 2; ++ks)                         \
        bfr[PL][ks] = *(const bf16x8*)(rb + (PL) * 8192 + ks * 1024 + lane * 16);

// Stage one 1 KB fragment-major unit of Bg into the LDS ring via DMA:
// unit u -> (plane, wn-group, ks); dest = wave-uniform base + lane*16 (HW).
__device__ __forceinline__ void stage_unit(const char* BgB, char* ringBase,
                                           int u, int it, int slotOff, int lane) {
    const int pl = u >> 3, rem = u & 7, g = rem >> 1, ks = rem & 1;
    const char* gsrc = BgB + (size_t)pl * 262144 + (size_t)(g * 32 + it) * 2048
                     + ks * 1024 + lane * 16;
    char* ldst = ringBase + slotOff + pl * 8192 + g * 2048 + ks * 1024;
    __builtin_amdgcn_global_load_lds(
        (const __attribute__((address_space(1))) void*)gsrc,
        (__attribute__((address_space(3))) void*)ldst, 16, 0, 0);
}

// ---------------------------------------------------------------------------
// Fused dist+argmin+gather. Grid 512, block 512 = 8 waves (2 wm x 4 wn),
// 2 blocks/CU. Block owns 64 px x all 2048 codes.
//   r10 lesson: B direct from L2 = 52.8 B/cyc/CU demand vs ~56 supply ->
//   L2-BW-bound (42%). r11 lesson: DMA dedup works, but 1 block/CU + a
//   barrier/iter couples all 16 waves with nothing to fill stalls (36%).
//   This round: DMA'd 2-slot ring (24 KB/iter/block, 26 B/cyc/CU demand)
//   AND 2 blocks/CU so each block's barrier drain overlaps the other's
//   compute (m114). Per-wave ~110 regs -> 4 waves/SIMD.
//   - 32 iters x 64 codes/block: wave wn handles codes wn*512+it*16..+16.
//   - 6 bf16 passes (hl,lh,mm,hm,mh,hh small->large): exact to ~2^-35.
//   - argmin: per-lane running best (n ascending -> strict <), shfl-16
//     col-reduce, LDS wn-reduce, lex (d,idx) = numpy first-min.
// ---------------------------------------------------------------------------
__global__ __launch_bounds__(512, 4)
void dist_fused_kernel(const float* __restrict__ laten,
                       const unsigned short* __restrict__ Bg,
                       const float* __restrict__ esq,
                       const float* __restrict__ cb,
                       float* __restrict__ out0, float* __restrict__ out1) {
    __shared__ __align__(16) char ring[49152];   // 2 x 24 KB B ring; A staging
    __shared__ float esqS[2048];                 // 8 KB

    const int tid  = threadIdx.x;
    const int lane = tid & 63;
    const int wave = tid >> 6;                   // 0..7
    const int wm   = wave & 1;                   // 32-px half
    const int wn   = wave >> 1;                  // 512-code quarter
    const int quad = lane >> 4, col = lane & 15;
    const int bx = blockIdx.x;
    const int bb = bx >> 4, hw0 = (bx & 15) * 64;   // 64 px contiguous in hw

    const char* BgB = (const char*)Bg;

    // ---- stage A into ring slot 0 (24 KB): split 8 dims of pixel p ----
    {
        const int p = tid & 63, dg = tid >> 6;   // dg 0..7 = kb unit
        const float* srcA = laten + (size_t)bb * 65536 + (size_t)dg * 8192 + hw0 + p;
        const int mt = p >> 4, mi = p & 15;      // mtile 0..3
        alignas(16) unsigned short hv[8], mv[8], lv[8];
#pragma unroll
        for (int j = 0; j < 8; ++j) {
            float v = srcA[(size_t)j << 10];     // coalesced across p
            unsigned short h = f2bf(v);
            float r1 = v - bf2f(h);
            unsigned short m = f2bf(r1);
            unsigned short l = f2bf(r1 - bf2f(m));
            hv[j] = h; mv[j] = m; lv[j] = l;
        }
        int u = ((mt * 8 + dg) << 8) + mi * 16;
        *(uint4*)(ring + u)         = *(uint4*)hv;   // plane h (8 KB stride)
        *(uint4*)(ring + 8192 + u)  = *(uint4*)mv;   // plane m
        *(uint4*)(ring + 16384 + u) = *(uint4*)lv;   // plane l
    }
    // stage e_sq (4 floats/thread)
    *(float4*)(esqS + tid * 4) = *(const float4*)(esq + tid * 4);
    __syncthreads();

    // ---- A fragments -> VGPRs: wave's 32-px half (48 regs resident; the
    //      staging area is clobbered by tile-0 DMA below -> forced residency)
    bf16x8 af[3][2][2];
#pragma unroll
    for (int pl = 0; pl < 3; ++pl)
#pragma unroll
        for (int mt = 0; mt < 2; ++mt)
#pragma unroll
            for (int ks = 0; ks < 2; ++ks)
                af[pl][mt][ks] = *(const bf16x8*)(ring + pl * 8192
                    + (((wm * 2 + mt) * 8 + ks * 4 + quad) << 8) + col * 16);
    __syncthreads();   // all waves done reading A before DMA clobbers slot 0

    // ---- stage B tile 0 into slot 0 (24 units: 3 per wave) ----
    stage_unit(BgB, ring, wave,      0, 0, lane);
    stage_unit(BgB, ring, wave + 8,  0, 0, lane);
    stage_unit(BgB, ring, wave + 16, 0, 0, lane);
    __syncthreads();   // drains own DMA (vmcnt 0) -> slot 0 ready for all

    float best[2][4];
    int   bidx[2][4];
#pragma unroll
    for (int mt = 0; mt < 2; ++mt)
#pragma unroll
        for (int r = 0; r < 4; ++r) { best[mt][r] = 3.4e38f; bidx[mt][r] = 0; }

    for (int it = 0; it < 32; ++it) {
        // issue next tile's DMA first: lands during this iter's MFMAs
        if (it < 31) {
            const int slotOff = ((it + 1) & 1) * 24576;
            stage_unit(BgB, ring, wave,      it + 1, slotOff, lane);
            stage_unit(BgB, ring, wave + 8,  it + 1, slotOff, lane);
            stage_unit(BgB, ring, wave + 16, it + 1, slotOff, lane);
        }

        // B fragments from LDS, consumption order (plane 2 first)
        const char* rb = ring + (it & 1) * 24576 + wn * 2048;
        bf16x8 bfr[3][2];
        LOAD_BFR(2)
        LOAD_BFR(0)
        LOAD_BFR(1)

        f32x4 acc[2];
#pragma unroll
        for (int mt = 0; mt < 2; ++mt) acc[mt] = {0.f, 0.f, 0.f, 0.f};

        // 6 passes small->large (hl, lh, mm, hm, mh, hh) — literal planes
        DO_PASS(0, 2)
        DO_PASS(2, 0)
        DO_PASS(1, 1)
        DO_PASS(0, 1)
        DO_PASS(1, 0)
        DO_PASS(0, 0)

        // running argmin; per-lane n strictly ascends across it
        const int n = wn * 512 + it * 16 + col;
        const float e = esqS[n];
#pragma unroll
        for (int mt = 0; mt < 2; ++mt)
#pragma unroll
            for (int r = 0; r < 4; ++r) {
                float d = fmaf(-2.f, acc[mt][r], e);
                if (d < best[mt][r]) { best[mt][r] = d; bidx[mt][r] = n; }
            }

        // one barrier/iter: publishes slot (it+1) (own DMA drained by the
        // implicit vmcnt(0)) and guards recycling of the slot just read.
        __syncthreads();
    }

    // ---- reduce: shfl over 16 cols, then LDS over the 4 wn quarters ----
    float* redD = (float*)ring;              // [64][4]
    int*   redI = (int*)(ring + 1024);       // [64][4]
    int*   idxF = (int*)(ring + 2048);       // [64]
#pragma unroll
    for (int mt = 0; mt < 2; ++mt)
#pragma unroll
        for (int r = 0; r < 4; ++r) {
            float d = best[mt][r];
            int   i = bidx[mt][r];
#pragma unroll
            for (int m = 1; m < 16; m <<= 1) {
                float od = __shfl_xor(d, m, 16);
                int   oi = __shfl_xor(i, m, 16);
                if (od < d || (od == d && oi < i)) { d = od; i = oi; }
            }
            if (col == 0) {
                int row = wm * 32 + mt * 16 + quad * 4 + r;   // pixel 0..63
                redD[row * 4 + wn] = d;
                redI[row * 4 + wn] = i;
            }
        }
    __syncthreads();

    if (tid < 64) {
        float bd = redD[tid * 4]; int bi = redI[tid * 4];
#pragma unroll
        for (int w = 1; w < 4; ++w) {
            float d = redD[tid * 4 + w]; int i = redI[tid * 4 + w];
            if (d < bd || (d == bd && i < bi)) { bd = d; bi = i; }
        }
        out0[bx * 64 + tid] = (float)bi;
        idxF[tid] = bi;
    }
    __syncthreads();

    // ---- fused gather: 64 px x 64 dims from the ORIGINAL fp32 codebook ----
    const int p = tid & 63, dg = tid >> 6;           // dg: 8 dims each
    const int idx = idxF[p];
    const float4* srcr = (const float4*)(cb + ((size_t)idx << 6) + dg * 8);
    float* o = out1 + (size_t)bb * 65536 + (size_t)dg * 8192 + hw0 + p;
    float4 v0 = srcr[0], v1 = srcr[1];
    o[(size_t)0 << 10] = v0.x; o[(size_t)1 << 10] = v0.y;
    o[(size_t)2 << 10] = v0.z; o[(size_t)3 << 10] = v0.w;
    o[(size_t)4 << 10] = v1.x; o[(size_t)5 << 10] = v1.y;
    o[(size_t)6 << 10] = v1.z; o[(size_t)7 << 10] = v1.w;
}

// ---------------------------------------------------------------------------
extern "C" void kernel_launch(void* const* d_in, const int* in_sizes, int n_in,
                              void* d_out, int out_size, void* d_ws, size_t ws_size,
                              hipStream_t stream) {
    const float* laten = (const float*)d_in[0];   // (32,64,32,32) fp32
    const float* cb    = (const float*)d_in[1];   // (2048,64) fp32

    float* out0 = (float*)d_out;                  // indices as float, N_PIX
    float* out1 = (float*)d_out + N_PIX;          // quant_laten, 2M

    // ws layout: esq 8 KB | Bg 768 KB   (~776 KB total)
    float* esq = (float*)d_ws;
    unsigned short* Bg = (unsigned short*)(esq + 2048);

    convert_b_kernel<<<8, 256, 0, stream>>>(cb, Bg, esq);

    dist_fused_kernel<<<512, 512, 0, stream>>>(laten, Bg, esq, cb, out0, out1);
}

// Round 13
// 104.922 us; speedup vs baseline: 1.0491x; 1.0238x over previous
//
#include <hip/hip_runtime.h>

// Problem constants (fixed by reference: B=32,D=64,H=32,W=32,K=2048)
#define N_PIX 32768   // B*H*W
#define DIM   64
#define KCODE 2048

typedef __attribute__((ext_vector_type(8))) short bf16x8;   // 8 bf16 = 4 VGPR
typedef __attribute__((ext_vector_type(4))) float f32x4;    // MFMA C/D

// bf16 round-to-nearest-even (manual, deterministic)
__device__ inline unsigned short f2bf(float v) {
    unsigned int u = __float_as_uint(v);
    return (unsigned short)((u + 0x7FFFu + ((u >> 16) & 1u)) >> 16);
}
__device__ inline float bf2f(unsigned short b) {
    return __uint_as_float(((unsigned int)b) << 16);
}

// ---------------------------------------------------------------------------
// convert_b v2: 16 threads/code, 128 blocks (ALL CUs; the old 8-block strided
// version was ~45 us — the hidden top line item of the whole bench).
// Thread t: code n = t>>4, sub = t&15 -> one coalesced float4 load, split to
// 3 bf16 planes (bit-identical math + Bg layout to r12), two 8-B stores per
// plane. e_sq via width-16 shfl butterfly (pairwise, ~np.sum order).
// ---------------------------------------------------------------------------
__global__ __launch_bounds__(256)
void convert_b_kernel(const float* __restrict__ cb, unsigned short* __restrict__ Bg,
                      float* __restrict__ esq) {
    const int t   = blockIdx.x * 256 + threadIdx.x;   // 32768 threads
    const int n   = t >> 4;                           // code id 0..2047
    const int sub = t & 15;                           // 16 thr per code
    const int ntile = n >> 4, ni = n & 15;

    const float4 v = *(const float4*)(cb + (size_t)n * DIM + sub * 4);  // coalesced

    unsigned int h01, h23, m01, m23, l01, l23;
    {
        unsigned short h, m, l;
        float r1;
        h = f2bf(v.x); r1 = v.x - bf2f(h); m = f2bf(r1); l = f2bf(r1 - bf2f(m));
        h01 = h;       m01 = m;       l01 = l;
        h = f2bf(v.y); r1 = v.y - bf2f(h); m = f2bf(r1); l = f2bf(r1 - bf2f(m));
        h01 |= (unsigned int)h << 16; m01 |= (unsigned int)m << 16; l01 |= (unsigned int)l << 16;
        h = f2bf(v.z); r1 = v.z - bf2f(h); m = f2bf(r1); l = f2bf(r1 - bf2f(m));
        h23 = h;       m23 = m;       l23 = l;
        h = f2bf(v.w); r1 = v.w - bf2f(h); m = f2bf(r1); l = f2bf(r1 - bf2f(m));
        h23 |= (unsigned int)h << 16; m23 |= (unsigned int)m << 16; l23 |= (unsigned int)l << 16;
    }

    // e_sq: per-thread partial then width-16 butterfly (pairwise order)
    float s = (v.x * v.x + v.y * v.y) + (v.z * v.z + v.w * v.w);
#pragma unroll
    for (int mk = 1; mk < 16; mk <<= 1) s += __shfl_xor(s, mk, 16);
    if (sub == 0) esq[n] = s;

    // dst: unit (ntile, kb=sub>>1), inner offset ni*16 + (sub&1)*8  — layout
    // identical to r12's Bg (dist kernel is byte-compatible, untouched).
    char* outb = (char*)Bg;
    const size_t u = ((((size_t)ntile) * 8 + (sub >> 1)) << 8) + ni * 16 + (sub & 1) * 8;
    uint2 hw2 = {h01, h23}, mw2 = {m01, m23}, lw2 = {l01, l23};
    *(uint2*)(outb + u)          = hw2;               // plane h (stride 256 KB)
    *(uint2*)(outb + 262144 + u) = mw2;               // plane m
    *(uint2*)(outb + 524288 + u) = lw2;               // plane l
}

// MFMA pass with LITERAL plane indices (SROA lesson: no array[array[i]]).
#define DO_PASS(APL, BPL)                                                    \
    _Pragma("unroll") for (int ks = 0; ks < 2; ++ks)                         \
    _Pragma("unroll") for (int mt = 0; mt < 2; ++mt)                         \
        acc[mt] = __builtin_amdgcn_mfma_f32_16x16x32_bf16(                   \
            af[APL][mt][ks], bfr[BPL][ks], acc[mt], 0, 0, 0);

// ds_read one plane's 2 B-fragments from the ring slot (consumption order
// at call sites: plane 2 first so DO_PASS(0,2) starts at partial lgkmcnt).
#define LOAD_BFR(PL)                                                         \
    _Pragma("unroll") for (int ks = 0; ks < 2; ++ks)                         \
        bfr[PL][ks] = *(const bf16x8*)(rb + (PL) * 8192 + ks * 1024 + lane * 16);

// Stage one 1 KB fragment-major unit of Bg into the LDS ring via DMA:
// unit u -> (plane, wn-group, ks); dest = wave-uniform base + lane*16 (HW).
__device__ __forceinline__ void stage_unit(const char* BgB, char* ringBase,
                                           int u, int it, int slotOff, int lane) {
    const int pl = u >> 3, rem = u & 7, g = rem >> 1, ks = rem & 1;
    const char* gsrc = BgB + (size_t)pl * 262144 + (size_t)(g * 32 + it) * 2048
                     + ks * 1024 + lane * 16;
    char* ldst = ringBase + slotOff + pl * 8192 + g * 2048 + ks * 1024;
    __builtin_amdgcn_global_load_lds(
        (const __attribute__((address_space(1))) void*)gsrc,
        (__attribute__((address_space(3))) void*)ldst, 16, 0, 0);
}

// ---------------------------------------------------------------------------
// Fused dist+argmin+gather — UNCHANGED from r12 (50.5 us, MfmaUtil 42%).
// Grid 512, block 512 = 8 waves (2 wm x 4 wn), 2 blocks/CU; DMA'd 2-slot
// LDS ring (24 KB/iter/block); 6 bf16 passes small->large, exact to ~2^-35;
// argmin per-lane (n ascending -> strict <), shfl-16 col-reduce, LDS
// wn-reduce, lex (d,idx) = numpy first-min.
// ---------------------------------------------------------------------------
__global__ __launch_bounds__(512, 4)
void dist_fused_kernel(const float* __restrict__ laten,
                       const unsigned short* __restrict__ Bg,
                       const float* __restrict__ esq,
                       const float* __restrict__ cb,
                       float* __restrict__ out0, float* __restrict__ out1) {
    __shared__ __align__(16) char ring[49152];   // 2 x 24 KB B ring; A staging
    __shared__ float esqS[2048];                 // 8 KB

    const int tid  = threadIdx.x;
    const int lane = tid & 63;
    const int wave = tid >> 6;                   // 0..7
    const int wm   = wave & 1;                   // 32-px half
    const int wn   = wave >> 1;                  // 512-code quarter
    const int quad = lane >> 4, col = lane & 15;
    const int bx = blockIdx.x;
    const int bb = bx >> 4, hw0 = (bx & 15) * 64;   // 64 px contiguous in hw

    const char* BgB = (const char*)Bg;

    // ---- stage A into ring slot 0 (24 KB): split 8 dims of pixel p ----
    {
        const int p = tid & 63, dg = tid >> 6;   // dg 0..7 = kb unit
        const float* srcA = laten + (size_t)bb * 65536 + (size_t)dg * 8192 + hw0 + p;
        const int mt = p >> 4, mi = p & 15;      // mtile 0..3
        alignas(16) unsigned short hv[8], mv[8], lv[8];
#pragma unroll
        for (int j = 0; j < 8; ++j) {
            float v = srcA[(size_t)j << 10];     // coalesced across p
            unsigned short h = f2bf(v);
            float r1 = v - bf2f(h);
            unsigned short m = f2bf(r1);
            unsigned short l = f2bf(r1 - bf2f(m));
            hv[j] = h; mv[j] = m; lv[j] = l;
        }
        int u = ((mt * 8 + dg) << 8) + mi * 16;
        *(uint4*)(ring + u)         = *(uint4*)hv;   // plane h (8 KB stride)
        *(uint4*)(ring + 8192 + u)  = *(uint4*)mv;   // plane m
        *(uint4*)(ring + 16384 + u) = *(uint4*)lv;   // plane l
    }
    // stage e_sq (4 floats/thread)
    *(float4*)(esqS + tid * 4) = *(const float4*)(esq + tid * 4);
    __syncthreads();

    // ---- A fragments -> VGPRs: wave's 32-px half (48 regs resident) ----
    bf16x8 af[3][2][2];
#pragma unroll
    for (int pl = 0; pl < 3; ++pl)
#pragma unroll
        for (int mt = 0; mt < 2; ++mt)
#pragma unroll
            for (int ks = 0; ks < 2; ++ks)
                af[pl][mt][ks] = *(const bf16x8*)(ring + pl * 8192
                    + (((wm * 2 + mt) * 8 + ks * 4 + quad) << 8) + col * 16);
    __syncthreads();   // all waves done reading A before DMA clobbers slot 0

    // ---- stage B tile 0 into slot 0 (24 units: 3 per wave) ----
    stage_unit(BgB, ring, wave,      0, 0, lane);
    stage_unit(BgB, ring, wave + 8,  0, 0, lane);
    stage_unit(BgB, ring, wave + 16, 0, 0, lane);
    __syncthreads();   // drains own DMA (vmcnt 0) -> slot 0 ready for all

    float best[2][4];
    int   bidx[2][4];
#pragma unroll
    for (int mt = 0; mt < 2; ++mt)
#pragma unroll
        for (int r = 0; r < 4; ++r) { best[mt][r] = 3.4e38f; bidx[mt][r] = 0; }

    for (int it = 0; it < 32; ++it) {
        // issue next tile's DMA first: lands during this iter's MFMAs
        if (it < 31) {
            const int slotOff = ((it + 1) & 1) * 24576;
            stage_unit(BgB, ring, wave,      it + 1, slotOff, lane);
            stage_unit(BgB, ring, wave + 8,  it + 1, slotOff, lane);
            stage_unit(BgB, ring, wave + 16, it + 1, slotOff, lane);
        }

        // B fragments from LDS, consumption order (plane 2 first)
        const char* rb = ring + (it & 1) * 24576 + wn * 2048;
        bf16x8 bfr[3][2];
        LOAD_BFR(2)
        LOAD_BFR(0)
        LOAD_BFR(1)

        f32x4 acc[2];
#pragma unroll
        for (int mt = 0; mt < 2; ++mt) acc[mt] = {0.f, 0.f, 0.f, 0.f};

        // 6 passes small->large (hl, lh, mm, hm, mh, hh) — literal planes
        DO_PASS(0, 2)
        DO_PASS(2, 0)
        DO_PASS(1, 1)
        DO_PASS(0, 1)
        DO_PASS(1, 0)
        DO_PASS(0, 0)

        // running argmin; per-lane n strictly ascends across it
        const int n = wn * 512 + it * 16 + col;
        const float e = esqS[n];
#pragma unroll
        for (int mt = 0; mt < 2; ++mt)
#pragma unroll
            for (int r = 0; r < 4; ++r) {
                float d = fmaf(-2.f, acc[mt][r], e);
                if (d < best[mt][r]) { best[mt][r] = d; bidx[mt][r] = n; }
            }

        // one barrier/iter: publishes slot (it+1) (own DMA drained by the
        // implicit vmcnt(0)) and guards recycling of the slot just read.
        __syncthreads();
    }

    // ---- reduce: shfl over 16 cols, then LDS over the 4 wn quarters ----
    float* redD = (float*)ring;              // [64][4]
    int*   redI = (int*)(ring + 1024);       // [64][4]
    int*   idxF = (int*)(ring + 2048);       // [64]
#pragma unroll
    for (int mt = 0; mt < 2; ++mt)
#pragma unroll
        for (int r = 0; r < 4; ++r) {
            float d = best[mt][r];
            int   i = bidx[mt][r];
#pragma unroll
            for (int m = 1; m < 16; m <<= 1) {
                float od = __shfl_xor(d, m, 16);
                int   oi = __shfl_xor(i, m, 16);
                if (od < d || (od == d && oi < i)) { d = od; i = oi; }
            }
            if (col == 0) {
                int row = wm * 32 + mt * 16 + quad * 4 + r;   // pixel 0..63
                redD[row * 4 + wn] = d;
                redI[row * 4 + wn] = i;
            }
        }
    __syncthreads();

    if (tid < 64) {
        float bd = redD[tid * 4]; int bi = redI[tid * 4];
#pragma unroll
        for (int w = 1; w < 4; ++w) {
            float d = redD[tid * 4 + w]; int i = redI[tid * 4 + w];
            if (d < bd || (d == bd && i < bi)) { bd = d; bi = i; }
        }
        out0[bx * 64 + tid] = (float)bi;
        idxF[tid] = bi;
    }
    __syncthreads();

    // ---- fused gather: 64 px x 64 dims from the ORIGINAL fp32 codebook ----
    const int p = tid & 63, dg = tid >> 6;           // dg: 8 dims each
    const int idx = idxF[p];
    const float4* srcr = (const float4*)(cb + ((size_t)idx << 6) + dg * 8);
    float* o = out1 + (size_t)bb * 65536 + (size_t)dg * 8192 + hw0 + p;
    float4 v0 = srcr[0], v1 = srcr[1];
    o[(size_t)0 << 10] = v0.x; o[(size_t)1 << 10] = v0.y;
    o[(size_t)2 << 10] = v0.z; o[(size_t)3 << 10] = v0.w;
    o[(size_t)4 << 10] = v1.x; o[(size_t)5 << 10] = v1.y;
    o[(size_t)6 << 10] = v1.z; o[(size_t)7 << 10] = v1.w;
}

// ---------------------------------------------------------------------------
extern "C" void kernel_launch(void* const* d_in, const int* in_sizes, int n_in,
                              void* d_out, int out_size, void* d_ws, size_t ws_size,
                              hipStream_t stream) {
    const float* laten = (const float*)d_in[0];   // (32,64,32,32) fp32
    const float* cb    = (const float*)d_in[1];   // (2048,64) fp32

    float* out0 = (float*)d_out;                  // indices as float, N_PIX
    float* out1 = (float*)d_out + N_PIX;          // quant_laten, 2M

    // ws layout: esq 8 KB | Bg 768 KB   (~776 KB total)
    float* esq = (float*)d_ws;
    unsigned short* Bg = (unsigned short*)(esq + 2048);

    convert_b_kernel<<<128, 256, 0, stream>>>(cb, Bg, esq);

    dist_fused_kernel<<<512, 512, 0, stream>>>(laten, Bg, esq, cb, out0, out1);
}